// Round 7
// baseline (366.975 us; speedup 1.0000x reference)
//
#include <hip/hip_runtime.h>
#include <cstdint>
#include <cstddef>

#define B_ 4
#define S_ 2048
#define D_ 1024
#define H_ 16

typedef unsigned short u16;
typedef unsigned int u32;
typedef __attribute__((ext_vector_type(8))) short bf16x8;
typedef __attribute__((ext_vector_type(4))) float f32x4;

__device__ __forceinline__ u16 f2bf(float f) {
  union { float f; u32 u; } x; x.f = f;
  u32 r = x.u + 0x7fffu + ((x.u >> 16) & 1u);
  return (u16)(r >> 16);
}

// packed fp32->bf16 pair (RTNE) — no builtin on gfx950, inline asm per T12
__device__ __forceinline__ u32 cvtpk_bf16(float lo, float hi) {
  u32 r;
  asm("v_cvt_pk_bf16_f32 %0, %1, %2" : "=v"(r) : "v"(lo), "v"(hi));
  return r;
}

__device__ __forceinline__ float max3f(float a, float b, float c) {
  return fmaxf(fmaxf(a, b), c);   // clang fuses to v_max3_f32
}

__device__ __forceinline__ f32x4 mfma16(bf16x8 a, bf16x8 b, f32x4 c) {
  return __builtin_amdgcn_mfma_f32_16x16x32_bf16(a, b, c, 0, 0, 0);
}

// global->LDS direct copy, 16B per lane. LDS dest is wave-uniform base
// (HW adds lane*16); global src is per-lane (pre-swizzled for bank-free reads).
__device__ __forceinline__ void gload_lds16(const u16* g, u16* l) {
  __builtin_amdgcn_global_load_lds((const __attribute__((address_space(1))) void*)g,
                                   (__attribute__((address_space(3))) void*)l,
                                   16, 0, 0);
}

// ---------------- fp32 -> bf16 conversion (memory-bound pre-pass) -------------
__global__ __launch_bounds__(256) void cvt_kernel(const float4* __restrict__ src,
                                                  uint2* __restrict__ dst, int n4) {
  int i = blockIdx.x * 256 + threadIdx.x;
  if (i < n4) {
    float4 v = src[i];
    uint2 o;
    o.x = cvtpk_bf16(v.x, v.y);
    o.y = cvtpk_bf16(v.z, v.w);
    dst[i] = o;
  }
}

// ---------------- fused QKV projection, 8-phase 256^2 schedule ----------------
// C[8192x3072] = A[8192x1024] * Bm[3072x1024]^T (both bf16 K-major).
// 8 waves (2M x 4N), BK=64 split in two K-32 halves, 2 dbuf x 4 half-tiles of
// 16KB each = 128KB LDS. Stage stream leads compute by 5 half-tiles ->
// steady-state s_waitcnt vmcnt(6) (3 half-tiles x 2 loads in flight).
// Epilogue: +bias, Q*0.125, scatter q/k [B,H,S,HD] and vT [B,H,HD,S].
__global__ __launch_bounds__(512, 2) void qkv_gemm(
    const u16* __restrict__ A, const u16* __restrict__ Bm,
    const float* __restrict__ bq, const float* __restrict__ bk,
    const float* __restrict__ bv,
    u16* __restrict__ qbuf, u16* __restrict__ kbuf, u16* __restrict__ vtbuf)
{
  extern __shared__ __align__(16) u16 lds[];       // 8 slots x 8192 u16 = 128KB

  const int bid = blockIdx.x;
  const int wg = (bid & 7) * 48 + (bid >> 3);      // XCD swizzle (384 % 8 == 0)
  const int bm = wg & 31;                          // 32 M-blocks of 256
  const int bn = wg >> 5;                          // 12 N-blocks of 256
  const int tid = threadIdx.x;
  const int w = tid >> 6, lane = tid & 63;
  const int g = lane >> 4, c = lane & 15;
  const int wr = w >> 2, wc = w & 3;               // 2M x 4N wave grid

  const u16* Ab = A  + (size_t)(bm * 256) * 1024;
  const u16* Bb = Bm + (size_t)(bn * 256) * 1024;

  // stage half-tile h (h = 4*T + q; q: 0=A-K0 1=B-K0 2=A-K1 3=B-K1) into slot h&7.
  // dest is linear; source column-block is inverse-swizzled (cb ^ (row>>1)&3).
  auto STAGE = [&](int h) {
    const int T = h >> 2, q = h & 3, kh = q >> 1;
    const u16* gp = (q & 1) ? Bb : Ab;
    u16* sb = lds + (h & 7) * 8192;
#pragma unroll
    for (int j = 0; j < 2; ++j) {
      const int blk = (w * 2 + j) * 64 + lane;
      const int row = blk >> 2;
      const int cb  = (blk & 3) ^ ((row >> 1) & 3);
      gload_lds16(gp + (size_t)row * 1024 + T * 64 + kh * 32 + cb * 8,
                  sb + (w * 2 + j) * 512);
    }
  };
  // read A fragment: M-frag m (16 rows), k-group g within the 32-col half
  auto LDA = [&](int slot, int m) -> bf16x8 {
    const int row = wr * 128 + m * 16 + c;
    const int blk = row * 4 + (g ^ ((row >> 1) & 3));
    return *(const bf16x8*)(lds + slot * 8192 + blk * 8);
  };
  auto LDB = [&](int slot, int n) -> bf16x8 {
    const int row = wc * 64 + n * 16 + c;
    const int blk = row * 4 + (g ^ ((row >> 1) & 3));
    return *(const bf16x8*)(lds + slot * 8192 + blk * 8);
  };

  f32x4 acc[8][4];
#pragma unroll
  for (int i = 0; i < 8; ++i)
#pragma unroll
    for (int j = 0; j < 4; ++j) acc[i][j] = (f32x4)0.0f;

  bf16x8 a0, a1, a2, a3, b0, b1, b2, b3;

#define MF4(ai, mi) \
  acc[mi][0] = mfma16(ai, b0, acc[mi][0]); \
  acc[mi][1] = mfma16(ai, b1, acc[mi][1]); \
  acc[mi][2] = mfma16(ai, b2, acc[mi][2]); \
  acc[mi][3] = mfma16(ai, b3, acc[mi][3]);

#define VM6 asm volatile("s_waitcnt vmcnt(6)" ::: "memory");

#define PHASE(SA, SB, MLO, STG, DOB, VM) \
  a0 = LDA(SA, MLO + 0); a1 = LDA(SA, MLO + 1); \
  a2 = LDA(SA, MLO + 2); a3 = LDA(SA, MLO + 3); \
  if (DOB) { b0 = LDB(SB, 0); b1 = LDB(SB, 1); b2 = LDB(SB, 2); b3 = LDB(SB, 3); } \
  STAGE(STG); \
  __builtin_amdgcn_s_barrier(); \
  asm volatile("s_waitcnt lgkmcnt(0)" ::: "memory"); \
  __builtin_amdgcn_sched_barrier(0); \
  __builtin_amdgcn_s_setprio(1); \
  MF4(a0, MLO + 0) MF4(a1, MLO + 1) MF4(a2, MLO + 2) MF4(a3, MLO + 3) \
  __builtin_amdgcn_s_setprio(0); \
  VM \
  __builtin_amdgcn_s_barrier();

#define KTILE(S0, HB) \
  PHASE(S0, S0 + 1, 0, HB + 0, 1, ) \
  PHASE(S0, S0 + 1, 4, HB + 1, 0, VM6) \
  PHASE(S0 + 2, S0 + 3, 0, HB + 2, 1, ) \
  PHASE(S0 + 2, S0 + 3, 4, HB + 3, 0, VM6)

  // prologue: stage halves 0..4, wait oldest two staged (A-K0,B-K0 of tile 0)
  STAGE(0); STAGE(1); STAGE(2); STAGE(3); STAGE(4);
  asm volatile("s_waitcnt vmcnt(6)" ::: "memory");
  __builtin_amdgcn_s_barrier();

  // main loop: tiles 0..13 (even tile in slots 0-3, odd in 4-7)
  for (int tp = 0; tp < 7; ++tp) {
    const int hb = 8 * tp + 5;
    KTILE(0, hb)
    KTILE(4, hb + 4)
  }

  // epilogue: finish staging halves 61..63, drain, compute tiles 14 & 15
  STAGE(61); STAGE(62); STAGE(63);
  asm volatile("s_waitcnt vmcnt(0)" ::: "memory");
  __builtin_amdgcn_s_barrier();

#define EPHASE(SA, SB, MLO, DOB) \
  a0 = LDA(SA, MLO + 0); a1 = LDA(SA, MLO + 1); \
  a2 = LDA(SA, MLO + 2); a3 = LDA(SA, MLO + 3); \
  if (DOB) { b0 = LDB(SB, 0); b1 = LDB(SB, 1); b2 = LDB(SB, 2); b3 = LDB(SB, 3); } \
  MF4(a0, MLO + 0) MF4(a1, MLO + 1) MF4(a2, MLO + 2) MF4(a3, MLO + 3)

  EPHASE(0, 1, 0, 1) EPHASE(0, 1, 4, 0) EPHASE(2, 3, 0, 1) EPHASE(2, 3, 4, 0)
  EPHASE(4, 5, 0, 1) EPHASE(4, 5, 4, 0) EPHASE(6, 7, 0, 1) EPHASE(6, 7, 4, 0)

  // ---- C epilogue: bias, scale, scatter (which-projection is block-uniform)
  const int which = bn >> 2;
  const float* bp = (which == 0) ? bq : (which == 1) ? bk : bv;
  const int m0r = bm * 256 + wr * 128;
#pragma unroll
  for (int n = 0; n < 4; ++n) {
    const int d = (bn & 3) * 256 + wc * 64 + n * 16 + c;
    const int hh = d >> 6, hd = d & 63;
    const float bias = bp[d];
#pragma unroll
    for (int m = 0; m < 8; ++m) {
#pragma unroll
      for (int r = 0; r < 4; ++r) {
        const int row = m0r + m * 16 + g * 4 + r;   // C/D: col=lane&15, row=4g+r
        const int bb = row >> 11, ss = row & 2047;
        float val = acc[m][n][r] + bias;
        if (which == 0) {
          val *= 0.125f;
          qbuf[((size_t)(bb * 16 + hh) * 2048 + ss) * 64 + hd] = f2bf(val);
        } else if (which == 1) {
          kbuf[((size_t)(bb * 16 + hh) * 2048 + ss) * 64 + hd] = f2bf(val);
        } else {
          vtbuf[((size_t)(bb * 16 + hh) * 64 + hd) * 2048 + ss] = f2bf(val);
        }
      }
    }
  }
#undef MF4
#undef VM6
#undef PHASE
#undef KTILE
#undef EPHASE
}

// ---------------- flash attention: 4 waves x 32 q-rows, KV tiles of 64 --------
__global__ __launch_bounds__(256) void attn_kernel(
    const u16* __restrict__ qbuf, const u16* __restrict__ kbuf,
    const u16* __restrict__ vtbuf, const float* __restrict__ pad,
    float* __restrict__ out)
{
  __shared__ __align__(16) u16 lK[64 * 64];        // K tile [kv][hd], swizzled
  __shared__ __align__(16) u16 lV[64 * 64];        // V^T tile [hd][kv], swizzled
  __shared__ __align__(16) u16 lP[4 * 32 * 64];    // per-wave P [q][kv], swizzled
  __shared__ __align__(16) float lMask[64];

  const int bid = blockIdx.x;
  const int wg = ((bid & 7) << 7) | (bid >> 3);    // XCD swizzle: same (b,h) co-XCD
  const int bh = wg >> 4;
  const int qb = wg & 15;
  const int b = bh >> 4;
  const int h = bh & 15;
  const int tid = threadIdx.x;
  const int wid = tid >> 6, lane = tid & 63;
  const int g = lane >> 4, c = lane & 15;
  const int q0 = qb * 128 + wid * 32;

  const u16* qp = qbuf + (size_t)bh * S_ * 64;
  const u16* kp = kbuf + (size_t)bh * S_ * 64;
  const u16* vp = vtbuf + (size_t)bh * 64 * S_;

  // Q fragments in registers (scale already folded in); also serve as MFMA B-operand.
  bf16x8 qf[2][2];
#pragma unroll
  for (int nt = 0; nt < 2; ++nt)
#pragma unroll
    for (int ks = 0; ks < 2; ++ks)
      qf[nt][ks] = *(const bf16x8*)(qp + (size_t)(q0 + nt * 16 + c) * 64 + ks * 32 + g * 8);

  f32x4 o[2][4];
#pragma unroll
  for (int mi = 0; mi < 2; ++mi)
#pragma unroll
    for (int nh = 0; nh < 4; ++nh) o[mi][nh] = (f32x4)0.0f;

  float mst[2] = {-3e38f, -3e38f};
  float lst[2] = {0.0f, 0.0f};

  const int lrow = lane >> 3;
  const int lcb = (lane & 7) ^ lrow;
  u16* lPw = lP + wid * (32 * 64);
  const float LOG2E = 1.44269504f;

  for (int j = 0; j < 32; ++j) {
    const int kv0 = j * 64;
#pragma unroll
    for (int jj = 0; jj < 2; ++jj) {
      const int r0 = wid * 16 + jj * 8;
      gload_lds16(kp + (size_t)(kv0 + r0 + lrow) * 64 + lcb * 8, lK + r0 * 64);
      gload_lds16(vp + (size_t)(r0 + lrow) * 2048 + kv0 + lcb * 8, lV + r0 * 64);
    }
    if (tid < 64) lMask[tid] = (1.0f - pad[b * S_ + kv0 + tid]) * (-1e9f);
    __syncthreads();

    // Swapped QK^T: St[kv][q] = K . Q  (per-lane: q = 16*nt + c, kv = 16*mt + 4g + r)
    f32x4 st[4][2];
#pragma unroll
    for (int mt = 0; mt < 4; ++mt) { st[mt][0] = (f32x4)0.0f; st[mt][1] = (f32x4)0.0f; }
#pragma unroll
    for (int ks = 0; ks < 2; ++ks) {
#pragma unroll
      for (int mt = 0; mt < 4; ++mt) {
        const int row = mt * 16 + c;
        const int cb = (ks * 4 + g) ^ (c & 7);
        const bf16x8 kf = *(const bf16x8*)(lK + row * 64 + cb * 8);
        st[mt][0] = mfma16(kf, qf[0][ks], st[mt][0]);
        st[mt][1] = mfma16(kf, qf[1][ks], st[mt][1]);
      }
    }

    // additive pad-mask bias per kv row (broadcast reads, vectorized)
    float mb[4][4];
#pragma unroll
    for (int mt = 0; mt < 4; ++mt) {
      const float4 m4 = *(const float4*)&lMask[mt * 16 + g * 4];
      mb[mt][0] = m4.x; mb[mt][1] = m4.y; mb[mt][2] = m4.z; mb[mt][3] = m4.w;
    }

#pragma unroll
    for (int nt = 0; nt < 2; ++nt) {
      // mask add + row-max via max3 trees
      float sv[16];
#pragma unroll
      for (int mt = 0; mt < 4; ++mt)
#pragma unroll
        for (int r = 0; r < 4; ++r) {
          const float v = st[mt][nt][r] + mb[mt][r];
          st[mt][nt][r] = v;
          sv[mt * 4 + r] = v;
        }
      float tmax = max3f(sv[0], sv[1], sv[2]);
      tmax = max3f(tmax, sv[3], sv[4]);
      tmax = max3f(tmax, sv[5], sv[6]);
      tmax = max3f(tmax, sv[7], sv[8]);
      tmax = max3f(tmax, sv[9], sv[10]);
      tmax = max3f(tmax, sv[11], sv[12]);
      tmax = max3f(tmax, sv[13], sv[14]);
      tmax = fmaxf(tmax, sv[15]);
      tmax = fmaxf(tmax, __shfl_xor(tmax, 16));
      tmax = fmaxf(tmax, __shfl_xor(tmax, 32));

      // T13 defer-max: only rescale when the running max grows by > 8
      if (!__all(tmax - mst[nt] <= 8.0f)) {
        const float mnew = fmaxf(mst[nt], tmax);
        const float fac = exp2f((mst[nt] - mnew) * LOG2E);
        mst[nt] = mnew;
        lst[nt] *= fac;
#pragma unroll
        for (int r = 0; r < 4; ++r) {
          const float fr = __shfl(fac, g * 4 + r);
#pragma unroll
          for (int nh = 0; nh < 4; ++nh) o[nt][nh][r] *= fr;
        }
      }

      const float ml = mst[nt] * LOG2E;
      float rsum = 0.0f;
#pragma unroll
      for (int mt = 0; mt < 4; ++mt)
#pragma unroll
        for (int r = 0; r < 4; ++r) {
          const float p = exp2f(fmaf(st[mt][nt][r], LOG2E, -ml));
          st[mt][nt][r] = p;
          rsum += p;
        }
      rsum += __shfl_xor(rsum, 16);
      rsum += __shfl_xor(rsum, 32);
      lst[nt] += rsum;

      // P -> LDS: packed v_cvt_pk_bf16_f32 pairs -> ds_write_b64, XOR-swizzled
#pragma unroll
      for (int mt = 0; mt < 4; ++mt) {
        uint2 pk;
        pk.x = cvtpk_bf16(st[mt][nt][0], st[mt][nt][1]);
        pk.y = cvtpk_bf16(st[mt][nt][2], st[mt][nt][3]);
        const int rowq = nt * 16 + c;
        const int cb = (2 * mt + (g >> 1)) ^ (c & 7);
        *(uint2*)(lPw + rowq * 64 + cb * 8 + (g & 1) * 4) = pk;
      }
    }

    // PV: O[q][hd] += P[q][kv] * V[kv][hd]   (A = P from LDS, B = V^T from LDS)
#pragma unroll
    for (int ks = 0; ks < 2; ++ks) {
      bf16x8 pa[2];
#pragma unroll
      for (int mi = 0; mi < 2; ++mi) {
        const int row = mi * 16 + c;
        const int cb = (ks * 4 + g) ^ (c & 7);
        pa[mi] = *(const bf16x8*)(lPw + row * 64 + cb * 8);
      }
#pragma unroll
      for (int nh = 0; nh < 4; ++nh) {
        const int row = nh * 16 + c;
        const int cb = (ks * 4 + g) ^ (c & 7);
        const bf16x8 vf = *(const bf16x8*)(lV + row * 64 + cb * 8);
#pragma unroll
        for (int mi = 0; mi < 2; ++mi)
          o[mi][nh] = mfma16(pa[mi], vf, o[mi][nh]);
      }
    }
    __syncthreads();
  }

  // finalize: divide by row sum, write [B,S,D] fp32
#pragma unroll
  for (int mi = 0; mi < 2; ++mi) {
#pragma unroll
    for (int r = 0; r < 4; ++r) {
      const float lr = __shfl(lst[mi], g * 4 + r);
      const float inv = 1.0f / lr;
      const int srow = q0 + mi * 16 + g * 4 + r;
      float* op = out + (size_t)(b * S_ + srow) * D_ + h * 64;
#pragma unroll
      for (int nh = 0; nh < 4; ++nh)
        op[nh * 16 + c] = o[mi][nh][r] * inv;
    }
  }
}

extern "C" void kernel_launch(void* const* d_in, const int* in_sizes, int n_in,
                              void* d_out, int out_size, void* d_ws, size_t ws_size,
                              hipStream_t stream) {
  const float* hs  = (const float*)d_in[0];
  const float* pad = (const float*)d_in[1];
  const float* wq  = (const float*)d_in[2];
  const float* bq  = (const float*)d_in[3];
  const float* wk  = (const float*)d_in[4];
  const float* bk  = (const float*)d_in[5];
  const float* wv  = (const float*)d_in[6];
  const float* bv  = (const float*)d_in[7];
  float* out = (float*)d_out;

  char* ws = (char*)d_ws;
  u16* Abf   = (u16*)ws;                    // 16 MB: hidden as bf16 [8192][1024]
  u16* Bbf   = (u16*)(ws + (16u << 20));    //  6 MB: [wq;wk;wv] bf16 [3072][1024]
  u16* qbuf  = (u16*)(ws + (22u << 20));    // 16 MB: Q bf16 [B,H,S,HD] (x0.125)
  u16* kbuf  = (u16*)(ws + (38u << 20));    // 16 MB: K bf16 [B,H,S,HD]
  u16* vtbuf = (u16*)(ws + (54u << 20));    // 16 MB: V^T bf16 [B,H,HD,S]

  // allow 128KB dynamic LDS for the 8-phase GEMM (idempotent, capture-safe)
  hipFuncSetAttribute(reinterpret_cast<const void*>(&qkv_gemm),
                      hipFuncAttributeMaxDynamicSharedMemorySize, 131072);

  cvt_kernel<<<8192, 256, 0, stream>>>((const float4*)hs, (uint2*)Abf, 2097152);
  cvt_kernel<<<1024, 256, 0, stream>>>((const float4*)wq, (uint2*)Bbf, 262144);
  cvt_kernel<<<1024, 256, 0, stream>>>((const float4*)wk, (uint2*)(Bbf + (1u << 20)), 262144);
  cvt_kernel<<<1024, 256, 0, stream>>>((const float4*)wv, (uint2*)(Bbf + (2u << 20)), 262144);

  qkv_gemm<<<384, 512, 131072, stream>>>(Abf, Bbf, bq, bk, bv, qbuf, kbuf, vtbuf);
  attn_kernel<<<1024, 256, 0, stream>>>(qbuf, kbuf, vtbuf, pad, out);
}

// Round 8
// 313.187 us; speedup vs baseline: 1.1717x; 1.1717x over previous
//
#include <hip/hip_runtime.h>
#include <cstdint>
#include <cstddef>

#define B_ 4
#define S_ 2048
#define D_ 1024
#define H_ 16

typedef unsigned short u16;
typedef unsigned int u32;
typedef __attribute__((ext_vector_type(8))) short bf16x8;
typedef __attribute__((ext_vector_type(4))) float f32x4;

// packed fp32->bf16 pair (RTNE) — no builtin on gfx950, inline asm per T12
__device__ __forceinline__ u32 cvtpk_bf16(float lo, float hi) {
  u32 r;
  asm("v_cvt_pk_bf16_f32 %0, %1, %2" : "=v"(r) : "v"(lo), "v"(hi));
  return r;
}

__device__ __forceinline__ u16 f2bf1(float v) {     // single value via cvt_pk
  return (u16)cvtpk_bf16(v, v);
}

// raw v_exp_f32 (2^x) — avoids any OCML multi-instruction expansion
__device__ __forceinline__ float exp2raw(float x) {
  float r;
  asm("v_exp_f32 %0, %1" : "=v"(r) : "v"(x));
  return r;
}

__device__ __forceinline__ float max3f(float a, float b, float c) {
  return fmaxf(fmaxf(a, b), c);   // clang fuses to v_max3_f32
}

__device__ __forceinline__ f32x4 mfma16(bf16x8 a, bf16x8 b, f32x4 c) {
  return __builtin_amdgcn_mfma_f32_16x16x32_bf16(a, b, c, 0, 0, 0);
}

// global->LDS direct copy, 16B per lane. LDS dest is wave-uniform base
// (HW adds lane*16); global src is per-lane (pre-swizzled for bank-free reads).
__device__ __forceinline__ void gload_lds16(const u16* g, u16* l) {
  __builtin_amdgcn_global_load_lds((const __attribute__((address_space(1))) void*)g,
                                   (__attribute__((address_space(3))) void*)l,
                                   16, 0, 0);
}

// ---------------- fp32 -> bf16 conversion (memory-bound pre-pass) -------------
__global__ __launch_bounds__(256) void cvt_kernel(const float4* __restrict__ src,
                                                  uint2* __restrict__ dst, int n4) {
  int i = blockIdx.x * 256 + threadIdx.x;
  if (i < n4) {
    float4 v = src[i];
    uint2 o;
    o.x = cvtpk_bf16(v.x, v.y);
    o.y = cvtpk_bf16(v.z, v.w);
    dst[i] = o;
  }
}

// ---------------- fused QKV projection: C[8192x3072] = A * B^T ---------------
// 2-phase 128^2 tile (proven ~5 blocks/CU, m114 inter-block overlap).
// Epilogue: +bias, Q*0.125, scatter q/k [B,H,S,HD]; V^T stores packed uint2.
__global__ __launch_bounds__(256) void qkv_gemm(
    const u16* __restrict__ A, const u16* __restrict__ Bm,
    const float* __restrict__ bq, const float* __restrict__ bk,
    const float* __restrict__ bv,
    u16* __restrict__ qbuf, u16* __restrict__ kbuf, u16* __restrict__ vtbuf)
{
  __shared__ __align__(16) u16 lA[128 * 64];
  __shared__ __align__(16) u16 lB[128 * 64];

  const int bid = blockIdx.x;
  const int wg = ((bid & 7) * 192) + (bid >> 3);   // XCD swizzle (1536 % 8 == 0)
  const int bm = wg & 63;                          // 64 M-blocks
  const int bn = wg >> 6;                          // 24 N-blocks
  const int tid = threadIdx.x;
  const int wid = tid >> 6, lane = tid & 63;
  const int g = lane >> 4, c = lane & 15;
  const int wm = wid & 1, wn = wid >> 1;
  const int lrow = lane >> 3;                      // 0..7
  const int lcb = (lane & 7) ^ lrow;               // pre-swizzled global col-block

  f32x4 acc[4][4];
#pragma unroll
  for (int i = 0; i < 4; ++i)
#pragma unroll
    for (int j = 0; j < 4; ++j) acc[i][j] = (f32x4)0.0f;

  const u16* Ab = A + (size_t)(bm * 128) * 1024;
  const u16* Bb = Bm + (size_t)(bn * 128) * 1024;

  for (int kt = 0; kt < 16; ++kt) {
    const int k0 = kt * 64;
#pragma unroll
    for (int jj = 0; jj < 4; ++jj) {
      const int r0 = wid * 32 + jj * 8;            // wave-uniform row chunk
      gload_lds16(Ab + (size_t)(r0 + lrow) * 1024 + k0 + lcb * 8, lA + r0 * 64);
      gload_lds16(Bb + (size_t)(r0 + lrow) * 1024 + k0 + lcb * 8, lB + r0 * 64);
    }
    __syncthreads();
#pragma unroll
    for (int ks = 0; ks < 2; ++ks) {
      bf16x8 af[4], bfv[4];
#pragma unroll
      for (int mi = 0; mi < 4; ++mi) {
        const int row = wm * 64 + mi * 16 + c;
        const int cb = (ks * 4 + g) ^ (c & 7);     // XOR de-swizzle on read
        af[mi] = *(const bf16x8*)(lA + row * 64 + cb * 8);
      }
#pragma unroll
      for (int ni = 0; ni < 4; ++ni) {
        const int row = wn * 64 + ni * 16 + c;
        const int cb = (ks * 4 + g) ^ (c & 7);
        bfv[ni] = *(const bf16x8*)(lB + row * 64 + cb * 8);
      }
#pragma unroll
      for (int mi = 0; mi < 4; ++mi)
#pragma unroll
        for (int ni = 0; ni < 4; ++ni)
          acc[mi][ni] = mfma16(af[mi], bfv[ni], acc[mi][ni]);
    }
    __syncthreads();
  }

  const int m0 = bm * 128 + wm * 64;
  const int n0 = bn * 128 + wn * 64;
#pragma unroll
  for (int ni = 0; ni < 4; ++ni) {
    const int col = n0 + ni * 16 + c;              // which-projection is wave-uniform
    const int which = col >> 10;
    const int d = col & 1023;
    const int hh = d >> 6, hd = d & 63;
    const float* bp = (which == 0) ? bq : (which == 1) ? bk : bv;
    const float bias = bp[d];
#pragma unroll
    for (int mi = 0; mi < 4; ++mi) {
      const int row0 = m0 + mi * 16 + g * 4;       // 4-aligned; r=0..3 consecutive
      const int bb = row0 >> 11, s0 = row0 & 2047;
      if (which == 2) {
        // V^T: r=0..3 consecutive in ss -> one packed 8B store
        uint2 pv;
        pv.x = cvtpk_bf16(acc[mi][ni][0] + bias, acc[mi][ni][1] + bias);
        pv.y = cvtpk_bf16(acc[mi][ni][2] + bias, acc[mi][ni][3] + bias);
        *(uint2*)&vtbuf[((size_t)(bb * 16 + hh) * 64 + hd) * 2048 + s0] = pv;
      } else {
        u16* dst = (which == 0) ? qbuf : kbuf;
        const float sc = (which == 0) ? 0.125f : 1.0f;
#pragma unroll
        for (int r = 0; r < 4; ++r) {
          dst[((size_t)(bb * 16 + hh) * 2048 + (s0 + r)) * 64 + hd] =
              f2bf1((acc[mi][ni][r] + bias) * sc);
        }
      }
    }
  }
}

// ---------------- flash attention: 4 waves x 32 q-rows, KV tiles of 64 --------
__global__ __launch_bounds__(256) void attn_kernel(
    const u16* __restrict__ qbuf, const u16* __restrict__ kbuf,
    const u16* __restrict__ vtbuf, const float* __restrict__ pad,
    float* __restrict__ out)
{
  __shared__ __align__(16) u16 lK[64 * 64];        // K tile [kv][hd], swizzled
  __shared__ __align__(16) u16 lV[64 * 64];        // V^T tile [hd][kv], swizzled
  __shared__ __align__(16) u16 lP[4 * 32 * 64];    // per-wave P [q][kv], swizzled
  __shared__ __align__(16) float lMask[64];

  const int bid = blockIdx.x;
  const int wg = ((bid & 7) << 7) | (bid >> 3);    // XCD swizzle: same (b,h) co-XCD
  const int bh = wg >> 4;
  const int qb = wg & 15;
  const int b = bh >> 4;
  const int h = bh & 15;
  const int tid = threadIdx.x;
  const int wid = tid >> 6, lane = tid & 63;
  const int g = lane >> 4, c = lane & 15;
  const int q0 = qb * 128 + wid * 32;

  const u16* qp = qbuf + (size_t)bh * S_ * 64;
  const u16* kp = kbuf + (size_t)bh * S_ * 64;
  const u16* vp = vtbuf + (size_t)bh * 64 * S_;

  // Q fragments in registers (scale already folded in); MFMA B-operand.
  bf16x8 qf[2][2];
#pragma unroll
  for (int nt = 0; nt < 2; ++nt)
#pragma unroll
    for (int ks = 0; ks < 2; ++ks)
      qf[nt][ks] = *(const bf16x8*)(qp + (size_t)(q0 + nt * 16 + c) * 64 + ks * 32 + g * 8);

  f32x4 o[2][4];
#pragma unroll
  for (int mi = 0; mi < 2; ++mi)
#pragma unroll
    for (int nh = 0; nh < 4; ++nh) o[mi][nh] = (f32x4)0.0f;

  float mst[2] = {-3e38f, -3e38f};
  float lst[2] = {0.0f, 0.0f};

  const int lrow = lane >> 3;
  const int lcb = (lane & 7) ^ lrow;
  u16* lPw = lP + wid * (32 * 64);
  const float LOG2E = 1.44269504f;

  for (int j = 0; j < 32; ++j) {
    const int kv0 = j * 64;
#pragma unroll
    for (int jj = 0; jj < 2; ++jj) {
      const int r0 = wid * 16 + jj * 8;
      gload_lds16(kp + (size_t)(kv0 + r0 + lrow) * 64 + lcb * 8, lK + r0 * 64);
      gload_lds16(vp + (size_t)(r0 + lrow) * 2048 + kv0 + lcb * 8, lV + r0 * 64);
    }
    if (tid < 64) lMask[tid] = (1.0f - pad[b * S_ + kv0 + tid]) * (-1e9f);
    __syncthreads();

    // Swapped QK^T: St[kv][q] = K . Q  (lane: q = 16*nt + c, kv = 16*mt + 4g + r)
    f32x4 st[4][2];
#pragma unroll
    for (int mt = 0; mt < 4; ++mt) { st[mt][0] = (f32x4)0.0f; st[mt][1] = (f32x4)0.0f; }
#pragma unroll
    for (int ks = 0; ks < 2; ++ks) {
#pragma unroll
      for (int mt = 0; mt < 4; ++mt) {
        const int row = mt * 16 + c;
        const int cb = (ks * 4 + g) ^ (c & 7);
        const bf16x8 kf = *(const bf16x8*)(lK + row * 64 + cb * 8);
        st[mt][0] = mfma16(kf, qf[0][ks], st[mt][0]);
        st[mt][1] = mfma16(kf, qf[1][ks], st[mt][1]);
      }
    }

    // wave-uniform skip when the pad mask is all-zero (common case: no padding)
    const bool mhit = !__all(lMask[lane] == 0.0f);
    float mb[4][4];
    if (mhit) {
#pragma unroll
      for (int mt = 0; mt < 4; ++mt) {
        const float4 m4 = *(const float4*)&lMask[mt * 16 + g * 4];
        mb[mt][0] = m4.x; mb[mt][1] = m4.y; mb[mt][2] = m4.z; mb[mt][3] = m4.w;
      }
    }

#pragma unroll
    for (int nt = 0; nt < 2; ++nt) {
      if (mhit) {
#pragma unroll
        for (int mt = 0; mt < 4; ++mt)
#pragma unroll
          for (int r = 0; r < 4; ++r) st[mt][nt][r] += mb[mt][r];
      }
      // row-max over the 16 local kv values (max3 tree), then 4-group reduce
      float tmax = max3f(st[0][nt][0], st[0][nt][1], st[0][nt][2]);
      tmax = max3f(tmax, st[0][nt][3], st[1][nt][0]);
      tmax = max3f(tmax, st[1][nt][1], st[1][nt][2]);
      tmax = max3f(tmax, st[1][nt][3], st[2][nt][0]);
      tmax = max3f(tmax, st[2][nt][1], st[2][nt][2]);
      tmax = max3f(tmax, st[2][nt][3], st[3][nt][0]);
      tmax = max3f(tmax, st[3][nt][1], st[3][nt][2]);
      tmax = fmaxf(tmax, st[3][nt][3]);
      tmax = fmaxf(tmax, __shfl_xor(tmax, 16));
      tmax = fmaxf(tmax, __shfl_xor(tmax, 32));

      // T13 defer-max: only rescale when the running max grows by > 8
      if (!__all(tmax - mst[nt] <= 8.0f)) {
        const float mnew = fmaxf(mst[nt], tmax);
        const float fac = exp2raw((mst[nt] - mnew) * LOG2E);
        mst[nt] = mnew;
        lst[nt] *= fac;
#pragma unroll
        for (int r = 0; r < 4; ++r) {
          const float fr = __shfl(fac, g * 4 + r);
#pragma unroll
          for (int nh = 0; nh < 4; ++nh) o[nt][nh][r] *= fr;
        }
      }

      const float ml = mst[nt] * LOG2E;
      float rsum = 0.0f;
#pragma unroll
      for (int mt = 0; mt < 4; ++mt)
#pragma unroll
        for (int r = 0; r < 4; ++r) {
          const float p = exp2raw(fmaf(st[mt][nt][r], LOG2E, -ml));
          st[mt][nt][r] = p;
          rsum += p;
        }
      rsum += __shfl_xor(rsum, 16);
      rsum += __shfl_xor(rsum, 32);
      lst[nt] += rsum;

      // P -> LDS: packed v_cvt_pk_bf16_f32 pairs -> ds_write_b64, XOR-swizzled
#pragma unroll
      for (int mt = 0; mt < 4; ++mt) {
        uint2 pk;
        pk.x = cvtpk_bf16(st[mt][nt][0], st[mt][nt][1]);
        pk.y = cvtpk_bf16(st[mt][nt][2], st[mt][nt][3]);
        const int rowq = nt * 16 + c;
        const int cb = (2 * mt + (g >> 1)) ^ (c & 7);
        *(uint2*)(lPw + rowq * 64 + cb * 8 + (g & 1) * 4) = pk;
      }
    }

    // PV: O[q][hd] += P[q][kv] * V[kv][hd]   (A = P from LDS, B = V^T from LDS)
#pragma unroll
    for (int ks = 0; ks < 2; ++ks) {
      bf16x8 pa[2];
#pragma unroll
      for (int mi = 0; mi < 2; ++mi) {
        const int row = mi * 16 + c;
        const int cb = (ks * 4 + g) ^ (c & 7);
        pa[mi] = *(const bf16x8*)(lPw + row * 64 + cb * 8);
      }
#pragma unroll
      for (int nh = 0; nh < 4; ++nh) {
        const int row = nh * 16 + c;
        const int cb = (ks * 4 + g) ^ (c & 7);
        const bf16x8 vf = *(const bf16x8*)(lV + row * 64 + cb * 8);
#pragma unroll
        for (int mi = 0; mi < 2; ++mi)
          o[mi][nh] = mfma16(pa[mi], vf, o[mi][nh]);
      }
    }
    __syncthreads();
  }

  // finalize: divide by row sum, write [B,S,D] fp32
#pragma unroll
  for (int mi = 0; mi < 2; ++mi) {
#pragma unroll
    for (int r = 0; r < 4; ++r) {
      const float lr = __shfl(lst[mi], g * 4 + r);
      const float inv = 1.0f / lr;
      const int srow = q0 + mi * 16 + g * 4 + r;
      float* op = out + (size_t)(b * S_ + srow) * D_ + h * 64;
#pragma unroll
      for (int nh = 0; nh < 4; ++nh)
        op[nh * 16 + c] = o[mi][nh][r] * inv;
    }
  }
}

extern "C" void kernel_launch(void* const* d_in, const int* in_sizes, int n_in,
                              void* d_out, int out_size, void* d_ws, size_t ws_size,
                              hipStream_t stream) {
  const float* hs  = (const float*)d_in[0];
  const float* pad = (const float*)d_in[1];
  const float* wq  = (const float*)d_in[2];
  const float* bq  = (const float*)d_in[3];
  const float* wk  = (const float*)d_in[4];
  const float* bk  = (const float*)d_in[5];
  const float* wv  = (const float*)d_in[6];
  const float* bv  = (const float*)d_in[7];
  float* out = (float*)d_out;

  char* ws = (char*)d_ws;
  u16* Abf   = (u16*)ws;                    // 16 MB: hidden as bf16 [8192][1024]
  u16* Bbf   = (u16*)(ws + (16u << 20));    //  6 MB: [wq;wk;wv] bf16 [3072][1024]
  u16* qbuf  = (u16*)(ws + (22u << 20));    // 16 MB: Q bf16 [B,H,S,HD] (x0.125)
  u16* kbuf  = (u16*)(ws + (38u << 20));    // 16 MB: K bf16 [B,H,S,HD]
  u16* vtbuf = (u16*)(ws + (54u << 20));    // 16 MB: V^T bf16 [B,H,HD,S]

  cvt_kernel<<<8192, 256, 0, stream>>>((const float4*)hs, (uint2*)Abf, 2097152);
  cvt_kernel<<<1024, 256, 0, stream>>>((const float4*)wq, (uint2*)Bbf, 262144);
  cvt_kernel<<<1024, 256, 0, stream>>>((const float4*)wk, (uint2*)(Bbf + (1u << 20)), 262144);
  cvt_kernel<<<1024, 256, 0, stream>>>((const float4*)wv, (uint2*)(Bbf + (2u << 20)), 262144);

  qkv_gemm<<<1536, 256, 0, stream>>>(Abf, Bbf, bq, bk, bv, qbuf, kbuf, vtbuf);
  attn_kernel<<<1024, 256, 0, stream>>>(qbuf, kbuf, vtbuf, pad, out);
}

// Round 11
// 304.270 us; speedup vs baseline: 1.2061x; 1.0293x over previous
//
#include <hip/hip_runtime.h>
#include <cstdint>
#include <cstddef>

#define B_ 4
#define S_ 2048
#define D_ 1024
#define H_ 16

typedef unsigned short u16;
typedef unsigned int u32;
typedef __attribute__((ext_vector_type(8))) short bf16x8;
typedef __attribute__((ext_vector_type(4))) float f32x4;

// packed fp32->bf16 pair (RTNE) — no builtin on gfx950, inline asm per T12
__device__ __forceinline__ u32 cvtpk_bf16(float lo, float hi) {
  u32 r;
  asm("v_cvt_pk_bf16_f32 %0, %1, %2" : "=v"(r) : "v"(lo), "v"(hi));
  return r;
}

__device__ __forceinline__ u16 f2bf1(float v) {     // single value via cvt_pk
  return (u16)cvtpk_bf16(v, v);
}

// raw v_exp_f32 (2^x) — avoids any OCML multi-instruction expansion
__device__ __forceinline__ float exp2raw(float x) {
  float r;
  asm("v_exp_f32 %0, %1" : "=v"(r) : "v"(x));
  return r;
}

__device__ __forceinline__ float max3f(float a, float b, float c) {
  return fmaxf(fmaxf(a, b), c);   // clang fuses to v_max3_f32
}

__device__ __forceinline__ f32x4 mfma16(bf16x8 a, bf16x8 b, f32x4 c) {
  return __builtin_amdgcn_mfma_f32_16x16x32_bf16(a, b, c, 0, 0, 0);
}

// global->LDS direct copy, 16B per lane. LDS dest is wave-uniform base
// (HW adds lane*16); global src is per-lane (pre-swizzled for bank-free reads).
__device__ __forceinline__ void gload_lds16(const u16* g, u16* l) {
  __builtin_amdgcn_global_load_lds((const __attribute__((address_space(1))) void*)g,
                                   (__attribute__((address_space(3))) void*)l,
                                   16, 0, 0);
}

// ---------------- fp32 -> bf16 conversion (memory-bound pre-pass) -------------
__global__ __launch_bounds__(256) void cvt_kernel(const float4* __restrict__ src,
                                                  uint2* __restrict__ dst, int n4) {
  int i = blockIdx.x * 256 + threadIdx.x;
  if (i < n4) {
    float4 v = src[i];
    uint2 o;
    o.x = cvtpk_bf16(v.x, v.y);
    o.y = cvtpk_bf16(v.z, v.w);
    dst[i] = o;
  }
}

// ---------------- fused QKV projection: C[8192x3072] = A * B^T ---------------
// 2-phase 128^2 tile (proven ~5 blocks/CU, m114 inter-block overlap).
// Epilogue: +bias, Q*0.125, scatter q/k [B,H,S,HD]; V^T stores packed uint2.
__global__ __launch_bounds__(256) void qkv_gemm(
    const u16* __restrict__ A, const u16* __restrict__ Bm,
    const float* __restrict__ bq, const float* __restrict__ bk,
    const float* __restrict__ bv,
    u16* __restrict__ qbuf, u16* __restrict__ kbuf, u16* __restrict__ vtbuf)
{
  __shared__ __align__(16) u16 lA[128 * 64];
  __shared__ __align__(16) u16 lB[128 * 64];

  const int bid = blockIdx.x;
  const int wg = ((bid & 7) * 192) + (bid >> 3);   // XCD swizzle (1536 % 8 == 0)
  const int bm = wg & 63;                          // 64 M-blocks
  const int bn = wg >> 6;                          // 24 N-blocks
  const int tid = threadIdx.x;
  const int wid = tid >> 6, lane = tid & 63;
  const int g = lane >> 4, c = lane & 15;
  const int wm = wid & 1, wn = wid >> 1;
  const int lrow = lane >> 3;                      // 0..7
  const int lcb = (lane & 7) ^ lrow;               // pre-swizzled global col-block

  f32x4 acc[4][4];
#pragma unroll
  for (int i = 0; i < 4; ++i)
#pragma unroll
    for (int j = 0; j < 4; ++j) acc[i][j] = (f32x4)0.0f;

  const u16* Ab = A + (size_t)(bm * 128) * 1024;
  const u16* Bb = Bm + (size_t)(bn * 128) * 1024;

  for (int kt = 0; kt < 16; ++kt) {
    const int k0 = kt * 64;
#pragma unroll
    for (int jj = 0; jj < 4; ++jj) {
      const int r0 = wid * 32 + jj * 8;            // wave-uniform row chunk
      gload_lds16(Ab + (size_t)(r0 + lrow) * 1024 + k0 + lcb * 8, lA + r0 * 64);
      gload_lds16(Bb + (size_t)(r0 + lrow) * 1024 + k0 + lcb * 8, lB + r0 * 64);
    }
    __syncthreads();
#pragma unroll
    for (int ks = 0; ks < 2; ++ks) {
      bf16x8 af[4], bfv[4];
#pragma unroll
      for (int mi = 0; mi < 4; ++mi) {
        const int row = wm * 64 + mi * 16 + c;
        const int cb = (ks * 4 + g) ^ (c & 7);     // XOR de-swizzle on read
        af[mi] = *(const bf16x8*)(lA + row * 64 + cb * 8);
      }
#pragma unroll
      for (int ni = 0; ni < 4; ++ni) {
        const int row = wn * 64 + ni * 16 + c;
        const int cb = (ks * 4 + g) ^ (c & 7);
        bfv[ni] = *(const bf16x8*)(lB + row * 64 + cb * 8);
      }
#pragma unroll
      for (int mi = 0; mi < 4; ++mi)
#pragma unroll
        for (int ni = 0; ni < 4; ++ni)
          acc[mi][ni] = mfma16(af[mi], bfv[ni], acc[mi][ni]);
    }
    __syncthreads();
  }

  const int m0 = bm * 128 + wm * 64;
  const int n0 = bn * 128 + wn * 64;
#pragma unroll
  for (int ni = 0; ni < 4; ++ni) {
    const int col = n0 + ni * 16 + c;              // which-projection is wave-uniform
    const int which = col >> 10;
    const int d = col & 1023;
    const int hh = d >> 6, hd = d & 63;
    const float* bp = (which == 0) ? bq : (which == 1) ? bk : bv;
    const float bias = bp[d];
#pragma unroll
    for (int mi = 0; mi < 4; ++mi) {
      const int row0 = m0 + mi * 16 + g * 4;       // 4-aligned; r=0..3 consecutive
      const int bb = row0 >> 11, s0 = row0 & 2047;
      if (which == 2) {
        // V^T: r=0..3 consecutive in ss -> one packed 8B store
        uint2 pv;
        pv.x = cvtpk_bf16(acc[mi][ni][0] + bias, acc[mi][ni][1] + bias);
        pv.y = cvtpk_bf16(acc[mi][ni][2] + bias, acc[mi][ni][3] + bias);
        *(uint2*)&vtbuf[((size_t)(bb * 16 + hh) * 64 + hd) * 2048 + s0] = pv;
      } else {
        u16* dst = (which == 0) ? qbuf : kbuf;
        const float sc = (which == 0) ? 0.125f : 1.0f;
#pragma unroll
        for (int r = 0; r < 4; ++r) {
          dst[((size_t)(bb * 16 + hh) * 2048 + (s0 + r)) * 64 + hd] =
              f2bf1((acc[mi][ni][r] + bias) * sc);
        }
      }
    }
  }
}

// ---------------- flash attention: 4 waves x 32 q-rows, KV tiles of 64 --------
// R9: K/V double-buffered (prefetch j+1 before compute j, single barrier/iter),
// pad-mask hoisted to LDS once, row-sum via MFMA(P, ones), setprio on MFMA.
__global__ __launch_bounds__(256) void attn_kernel(
    const u16* __restrict__ qbuf, const u16* __restrict__ kbuf,
    const u16* __restrict__ vtbuf, const float* __restrict__ pad,
    float* __restrict__ out)
{
  __shared__ __align__(16) u16 lK[2][64 * 64];     // K tiles [kv][hd], swizzled
  __shared__ __align__(16) u16 lV[2][64 * 64];     // V^T tiles [hd][kv], swizzled
  __shared__ __align__(16) u16 lP[4 * 32 * 64];    // per-wave P [q][kv], swizzled
  __shared__ __align__(16) float lMaskAll[2048];   // (1-pad)*-1e9 for whole row

  const int bid = blockIdx.x;
  const int wg = ((bid & 7) << 7) | (bid >> 3);    // XCD swizzle: same (b,h) co-XCD
  const int bh = wg >> 4;
  const int qb = wg & 15;
  const int b = bh >> 4;
  const int h = bh & 15;
  const int tid = threadIdx.x;
  const int wid = tid >> 6, lane = tid & 63;
  const int g = lane >> 4, c = lane & 15;
  const int q0 = qb * 128 + wid * 32;

  const u16* qp = qbuf + (size_t)bh * S_ * 64;
  const u16* kp = kbuf + (size_t)bh * S_ * 64;
  const u16* vp = vtbuf + (size_t)bh * 64 * S_;

  // one-time: pad -> additive-bias table in LDS
  {
    const float4* p4 = (const float4*)(pad + (size_t)b * S_);
#pragma unroll
    for (int i = 0; i < 2; ++i) {
      const int idx = tid + i * 256;               // 0..511 float4s
      const float4 v = p4[idx];
      float4 m;
      m.x = (1.0f - v.x) * (-1e9f); m.y = (1.0f - v.y) * (-1e9f);
      m.z = (1.0f - v.z) * (-1e9f); m.w = (1.0f - v.w) * (-1e9f);
      *(float4*)&lMaskAll[idx * 4] = m;
    }
  }

  // Q fragments in registers (scale folded in); MFMA B-operand.
  bf16x8 qf[2][2];
#pragma unroll
  for (int nt = 0; nt < 2; ++nt)
#pragma unroll
    for (int ks = 0; ks < 2; ++ks)
      qf[nt][ks] = *(const bf16x8*)(qp + (size_t)(q0 + nt * 16 + c) * 64 + ks * 32 + g * 8);

  f32x4 o[2][4];
#pragma unroll
  for (int mi = 0; mi < 2; ++mi)
#pragma unroll
    for (int nh = 0; nh < 4; ++nh) o[mi][nh] = (f32x4)0.0f;
  f32x4 lsum[2];
  lsum[0] = (f32x4)0.0f; lsum[1] = (f32x4)0.0f;
  float mst[2] = {-3e38f, -3e38f};

  const int lrow = lane >> 3;
  const int lcb = (lane & 7) ^ lrow;
  u16* lPw = lP + wid * (32 * 64);
  const float LOG2E = 1.44269504f;

  const short one_bf = (short)0x3F80;
  const bf16x8 vones = {one_bf, one_bf, one_bf, one_bf, one_bf, one_bf, one_bf, one_bf};

  auto stageKV = [&](int jt, int bufn) {
    const int kv0 = jt * 64;
#pragma unroll
    for (int jj = 0; jj < 2; ++jj) {
      const int r0 = wid * 16 + jj * 8;
      gload_lds16(kp + (size_t)(kv0 + r0 + lrow) * 64 + lcb * 8, &lK[bufn][r0 * 64]);
      gload_lds16(vp + (size_t)(r0 + lrow) * 2048 + kv0 + lcb * 8, &lV[bufn][r0 * 64]);
    }
  };

  // prologue: tile 0 into buf 0 (also covers lMaskAll + qf visibility)
  stageKV(0, 0);
  asm volatile("s_waitcnt vmcnt(0)" ::: "memory");
  __syncthreads();

  int cur = 0;
  for (int j = 0; j < 32; ++j) {
    const int kv0 = j * 64;
    if (j < 31) stageKV(j + 1, cur ^ 1);           // prefetch under compute

    // Swapped QK^T: St[kv][q] = K . Q  (lane: q = 16*nt + c, kv = 16*mt + 4g + r)
    f32x4 st[4][2];
#pragma unroll
    for (int mt = 0; mt < 4; ++mt) { st[mt][0] = (f32x4)0.0f; st[mt][1] = (f32x4)0.0f; }
    __builtin_amdgcn_s_setprio(1);
#pragma unroll
    for (int ks = 0; ks < 2; ++ks) {
#pragma unroll
      for (int mt = 0; mt < 4; ++mt) {
        const int row = mt * 16 + c;
        const int cb = (ks * 4 + g) ^ (c & 7);
        const bf16x8 kf = *(const bf16x8*)(&lK[cur][row * 64 + cb * 8]);
        st[mt][0] = mfma16(kf, qf[0][ks], st[mt][0]);
        st[mt][1] = mfma16(kf, qf[1][ks], st[mt][1]);
      }
    }
    __builtin_amdgcn_s_setprio(0);

    // wave-uniform skip when this kv window's pad mask is all-zero
    const bool mhit = !__all(lMaskAll[kv0 + lane] == 0.0f);
    float mb[4][4];
    if (mhit) {
#pragma unroll
      for (int mt = 0; mt < 4; ++mt) {
        const float4 m4 = *(const float4*)&lMaskAll[kv0 + mt * 16 + g * 4];
        mb[mt][0] = m4.x; mb[mt][1] = m4.y; mb[mt][2] = m4.z; mb[mt][3] = m4.w;
      }
    }

#pragma unroll
    for (int nt = 0; nt < 2; ++nt) {
      if (mhit) {
#pragma unroll
        for (int mt = 0; mt < 4; ++mt)
#pragma unroll
          for (int r = 0; r < 4; ++r) st[mt][nt][r] += mb[mt][r];
      }
      // row-max over the 16 local kv values (max3 tree), then 4-group reduce
      float tmax = max3f(st[0][nt][0], st[0][nt][1], st[0][nt][2]);
      tmax = max3f(tmax, st[0][nt][3], st[1][nt][0]);
      tmax = max3f(tmax, st[1][nt][1], st[1][nt][2]);
      tmax = max3f(tmax, st[1][nt][3], st[2][nt][0]);
      tmax = max3f(tmax, st[2][nt][1], st[2][nt][2]);
      tmax = max3f(tmax, st[2][nt][3], st[3][nt][0]);
      tmax = max3f(tmax, st[3][nt][1], st[3][nt][2]);
      tmax = fmaxf(tmax, st[3][nt][3]);
      tmax = fmaxf(tmax, __shfl_xor(tmax, 16));
      tmax = fmaxf(tmax, __shfl_xor(tmax, 32));

      // T13 defer-max: only rescale when the running max grows by > 8
      if (!__all(tmax - mst[nt] <= 8.0f)) {
        const float mnew = fmaxf(mst[nt], tmax);
        const float fac = exp2raw((mst[nt] - mnew) * LOG2E);
        mst[nt] = mnew;
#pragma unroll
        for (int r = 0; r < 4; ++r) {
          const float fr = __shfl(fac, g * 4 + r);
          lsum[nt][r] *= fr;
#pragma unroll
          for (int nh = 0; nh < 4; ++nh) o[nt][nh][r] *= fr;
        }
      }

      const float ml = mst[nt] * LOG2E;
#pragma unroll
      for (int mt = 0; mt < 4; ++mt)
#pragma unroll
        for (int r = 0; r < 4; ++r)
          st[mt][nt][r] = exp2raw(fmaf(st[mt][nt][r], LOG2E, -ml));

      // P -> LDS: packed v_cvt_pk_bf16_f32 pairs -> ds_write_b64, XOR-swizzled
#pragma unroll
      for (int mt = 0; mt < 4; ++mt) {
        uint2 pk;
        pk.x = cvtpk_bf16(st[mt][nt][0], st[mt][nt][1]);
        pk.y = cvtpk_bf16(st[mt][nt][2], st[mt][nt][3]);
        const int rowq = nt * 16 + c;
        const int cb = (2 * mt + (g >> 1)) ^ (c & 7);
        *(uint2*)(lPw + rowq * 64 + cb * 8 + (g & 1) * 4) = pk;
      }
    }

    // PV: O[q][hd] += P[q][kv] * V[kv][hd]; row-sum via MFMA(P, ones)
    __builtin_amdgcn_s_setprio(1);
#pragma unroll
    for (int ks = 0; ks < 2; ++ks) {
      bf16x8 pa[2];
#pragma unroll
      for (int mi = 0; mi < 2; ++mi) {
        const int row = mi * 16 + c;
        const int cb = (ks * 4 + g) ^ (c & 7);
        pa[mi] = *(const bf16x8*)(lPw + row * 64 + cb * 8);
      }
      lsum[0] = mfma16(pa[0], vones, lsum[0]);
      lsum[1] = mfma16(pa[1], vones, lsum[1]);
#pragma unroll
      for (int nh = 0; nh < 4; ++nh) {
        const int row = nh * 16 + c;
        const int cb = (ks * 4 + g) ^ (c & 7);
        const bf16x8 vf = *(const bf16x8*)(&lV[cur][row * 64 + cb * 8]);
#pragma unroll
        for (int mi = 0; mi < 2; ++mi)
          o[mi][nh] = mfma16(pa[mi], vf, o[mi][nh]);
      }
    }
    __builtin_amdgcn_s_setprio(0);

    asm volatile("s_waitcnt vmcnt(0)" ::: "memory");  // j+1 staged (hidden by compute)
    __syncthreads();                                   // visible + buf[cur] free
    cur ^= 1;
  }

  // finalize: divide by MFMA row sum (already in D-layout), write [B,S,D] fp32
#pragma unroll
  for (int mi = 0; mi < 2; ++mi) {
#pragma unroll
    for (int r = 0; r < 4; ++r) {
      const float inv = 1.0f / lsum[mi][r];
      const int srow = q0 + mi * 16 + g * 4 + r;
      float* op = out + (size_t)(b * S_ + srow) * D_ + h * 64;
#pragma unroll
      for (int nh = 0; nh < 4; ++nh)
        op[nh * 16 + c] = o[mi][nh][r] * inv;
    }
  }
}

extern "C" void kernel_launch(void* const* d_in, const int* in_sizes, int n_in,
                              void* d_out, int out_size, void* d_ws, size_t ws_size,
                              hipStream_t stream) {
  const float* hs  = (const float*)d_in[0];
  const float* pad = (const float*)d_in[1];
  const float* wq  = (const float*)d_in[2];
  const float* bq  = (const float*)d_in[3];
  const float* wk  = (const float*)d_in[4];
  const float* bk  = (const float*)d_in[5];
  const float* wv  = (const float*)d_in[6];
  const float* bv  = (const float*)d_in[7];
  float* out = (float*)d_out;

  char* ws = (char*)d_ws;
  u16* Abf   = (u16*)ws;                    // 16 MB: hidden as bf16 [8192][1024]
  u16* Bbf   = (u16*)(ws + (16u << 20));    //  6 MB: [wq;wk;wv] bf16 [3072][1024]
  u16* qbuf  = (u16*)(ws + (22u << 20));    // 16 MB: Q bf16 [B,H,S,HD] (x0.125)
  u16* kbuf  = (u16*)(ws + (38u << 20));    // 16 MB: K bf16 [B,H,S,HD]
  u16* vtbuf = (u16*)(ws + (54u << 20));    // 16 MB: V^T bf16 [B,H,HD,S]

  cvt_kernel<<<8192, 256, 0, stream>>>((const float4*)hs, (uint2*)Abf, 2097152);
  cvt_kernel<<<1024, 256, 0, stream>>>((const float4*)wq, (uint2*)Bbf, 262144);
  cvt_kernel<<<1024, 256, 0, stream>>>((const float4*)wk, (uint2*)(Bbf + (1u << 20)), 262144);
  cvt_kernel<<<1024, 256, 0, stream>>>((const float4*)wv, (uint2*)(Bbf + (2u << 20)), 262144);

  qkv_gemm<<<1536, 256, 0, stream>>>(Abf, Bbf, bq, bk, bv, qbuf, kbuf, vtbuf);
  attn_kernel<<<1024, 256, 0, stream>>>(qbuf, kbuf, vtbuf, pad, out);
}